// Round 1
// baseline (435.096 us; speedup 1.0000x reference)
//
#include <hip/hip_runtime.h>

#define NPIX   1024   // 32*32
#define BATCH  16
#define CIN    256
#define NQKV   1536   // 512 q + 512 k + 512 v
#define INNER  512
#define HEADS  8
#define DH     64

// ---------------------------------------------------------------------------
// Weight transpose: Wt[c][o] (o = q|k|v channel), Wot[i][co]
// ---------------------------------------------------------------------------
__global__ void transpose_w(const float* __restrict__ Wq, const float* __restrict__ Wkv,
                            const float* __restrict__ Wo,
                            float* __restrict__ Wt, float* __restrict__ Wot) {
    int idx = blockIdx.x * blockDim.x + threadIdx.x;
    const int T1 = CIN * NQKV;   // 393216
    const int T2 = INNER * CIN;  // 131072
    if (idx < T1) {
        int c = idx / NQKV, o = idx % NQKV;
        Wt[idx] = (o < 512) ? Wq[o * CIN + c] : Wkv[(o - 512) * CIN + c];
    } else if (idx < T1 + T2) {
        int j = idx - T1;
        int i = j / CIN, co = j % CIN;
        Wot[j] = Wo[co * INNER + i];
    }
}

// ---------------------------------------------------------------------------
// GEMM1: qkv[m][o] = sum_c x[b,c,p] * Wt[c][o]   (M=16384, N=1536, K=256)
// x layout: [b, c, 1024] (pixel-contiguous). Output split into qs/ks/vs,
// each [m][512] pixel-major.
// ---------------------------------------------------------------------------
__global__ __launch_bounds__(256) void qkv_gemm(const float* __restrict__ x,
        const float* __restrict__ Wt,
        float* __restrict__ qs, float* __restrict__ ks, float* __restrict__ vs) {
    __shared__ float Xs[16][64];
    __shared__ float Wsh[16][64];
    const int o0 = blockIdx.x * 64;
    const int m0 = blockIdx.y * 64;
    const int b  = m0 >> 10;
    const int p0 = m0 & 1023;
    const int t  = threadIdx.x;
    const int to = t & 15;   // o minor (for coalesced o-contiguous writes)
    const int tm = t >> 4;

    float acc[4][4] = {};
    for (int c0 = 0; c0 < CIN; c0 += 16) {
#pragma unroll
        for (int ld = 0; ld < 4; ld++) {
            int idx = t + ld * 256;
            int kk = idx >> 6, mm = idx & 63;
            Xs[kk][mm]  = x[(b * CIN + c0 + kk) * NPIX + p0 + mm];
            Wsh[kk][mm] = Wt[(c0 + kk) * NQKV + o0 + mm];
        }
        __syncthreads();
#pragma unroll
        for (int kk = 0; kk < 16; kk++) {
            float4 av = *reinterpret_cast<const float4*>(&Xs[kk][tm * 4]);
            float4 bv = *reinterpret_cast<const float4*>(&Wsh[kk][to * 4]);
            float a[4] = {av.x, av.y, av.z, av.w};
            float bb[4] = {bv.x, bv.y, bv.z, bv.w};
#pragma unroll
            for (int i = 0; i < 4; i++)
#pragma unroll
                for (int j = 0; j < 4; j++)
                    acc[i][j] = fmaf(a[i], bb[j], acc[i][j]);
        }
        __syncthreads();
    }
    const int sel = o0 >> 9;                       // 0:q 1:k 2:v (tile never straddles)
    float* buf = (sel == 0) ? qs : (sel == 1) ? ks : vs;
    const int ob = o0 - sel * 512;
#pragma unroll
    for (int i = 0; i < 4; i++) {
        int m = m0 + tm * 4 + i;
        float4 v4 = make_float4(acc[i][0], acc[i][1], acc[i][2], acc[i][3]);
        *reinterpret_cast<float4*>(&buf[m * INNER + ob + to * 4]) = v4;
    }
}

// ---------------------------------------------------------------------------
// Attention: one 64-lane wave per (b, pixel, head). lane = d.
// Zero-padded windows: OOB positions have logit exactly 0 (included in
// softmax) and contribute 0 to PV. attn written to second output.
// po aliases qs (each wave reads its own q segment, then overwrites it).
// ---------------------------------------------------------------------------
__global__ __launch_bounds__(256) void attn_kernel(const float* qs,
        const float* __restrict__ ks, const float* __restrict__ vs,
        float* po, float* __restrict__ attn_out) {
    const int gw   = blockIdx.x * 4 + (threadIdx.x >> 6);
    const int lane = threadIdx.x & 63;
    const int h = gw & 7;
    const int m = gw >> 3;        // b*1024 + p
    const int b = m >> 10;
    const int p = m & 1023;
    const int py = p >> 5, px = p & 31;

    const float q = qs[m * INNER + h * DH + lane];

    float dots[9];
    int   nb[9];
    bool  ok[9];
#pragma unroll
    for (int w = 0; w < 9; w++) {
        int dy = w / 3 - 1, dx = w % 3 - 1;
        int ny = py + dy, nx = px + dx;
        bool in = ((unsigned)ny < 32u) && ((unsigned)nx < 32u);
        ok[w] = in;
        int nm = b * NPIX + ny * 32 + nx;
        nb[w] = nm;
        float d = 0.f;
        if (in) d = q * ks[nm * INNER + h * DH + lane];
#pragma unroll
        for (int off = 32; off; off >>= 1) d += __shfl_xor(d, off);
        dots[w] = d * 0.125f;    // OOB: exact 0 (matches zero-pad semantics)
    }

    float mx = dots[0];
#pragma unroll
    for (int w = 1; w < 9; w++) mx = fmaxf(mx, dots[w]);
    float e[9], s = 0.f;
#pragma unroll
    for (int w = 0; w < 9; w++) { e[w] = __expf(dots[w] - mx); s += e[w]; }
    const float inv = 1.f / s;

    float o = 0.f;
#pragma unroll
    for (int w = 0; w < 9; w++)
        if (ok[w]) o += (e[w] * inv) * vs[nb[w] * INNER + h * DH + lane];
    po[m * INNER + h * DH + lane] = o;

    float myattn = 0.f;
#pragma unroll
    for (int w = 0; w < 9; w++) myattn = (lane == w) ? e[w] * inv : myattn;
    if (lane < 9)
        attn_out[((b * HEADS + h) * NPIX + p) * 9 + lane] = myattn;
}

// ---------------------------------------------------------------------------
// GEMM2: out[b, o, p] = sum_i po[m][i] * Wot[i][o] + bo[o]
// (M=16384, N=256, K=512)
// ---------------------------------------------------------------------------
__global__ __launch_bounds__(256) void out_gemm(const float* __restrict__ po,
        const float* __restrict__ Wot, const float* __restrict__ bo,
        float* __restrict__ out) {
    __shared__ float As[16][68];   // pad 68: avoids 16-way write conflict, keeps 16B align
    __shared__ float Wsh[16][64];
    const int o0 = blockIdx.x * 64;
    const int m0 = blockIdx.y * 64;
    const int b  = m0 >> 10;
    const int p0 = m0 & 1023;
    const int t  = threadIdx.x;
    const int tm = t & 15;   // p minor (for coalesced p-contiguous writes)
    const int to = t >> 4;

    float acc[4][4] = {};
    for (int c0 = 0; c0 < INNER; c0 += 16) {
#pragma unroll
        for (int ld = 0; ld < 4; ld++) {
            int idx = t + ld * 256;
            int kk = idx & 15, mm = idx >> 4;     // k minor: coalesced row-major reads
            As[kk][mm] = po[(m0 + mm) * INNER + c0 + kk];
        }
#pragma unroll
        for (int ld = 0; ld < 4; ld++) {
            int idx = t + ld * 256;
            int kk = idx >> 6, oo = idx & 63;
            Wsh[kk][oo] = Wot[(c0 + kk) * CIN + o0 + oo];
        }
        __syncthreads();
#pragma unroll
        for (int kk = 0; kk < 16; kk++) {
            float4 av = *reinterpret_cast<const float4*>(&As[kk][tm * 4]);
            float4 bv = *reinterpret_cast<const float4*>(&Wsh[kk][to * 4]);
            float a[4] = {av.x, av.y, av.z, av.w};
            float bb[4] = {bv.x, bv.y, bv.z, bv.w};
#pragma unroll
            for (int i = 0; i < 4; i++)
#pragma unroll
                for (int j = 0; j < 4; j++)
                    acc[i][j] = fmaf(a[i], bb[j], acc[i][j]);
        }
        __syncthreads();
    }
#pragma unroll
    for (int j = 0; j < 4; j++) {
        int o = o0 + to * 4 + j;
        float bias = bo[o];
        float4 v4 = make_float4(acc[0][j] + bias, acc[1][j] + bias,
                                acc[2][j] + bias, acc[3][j] + bias);
        *reinterpret_cast<float4*>(&out[(b * CIN + o) * NPIX + p0 + tm * 4]) = v4;
    }
}

// ---------------------------------------------------------------------------
extern "C" void kernel_launch(void* const* d_in, const int* in_sizes, int n_in,
                              void* d_out, int out_size, void* d_ws, size_t ws_size,
                              hipStream_t stream) {
    const float* x   = (const float*)d_in[0];
    const float* Wq  = (const float*)d_in[1];
    const float* Wkv = (const float*)d_in[2];
    const float* Wo  = (const float*)d_in[3];
    const float* bo  = (const float*)d_in[4];

    float* out  = (float*)d_out;                       // [16,256,32,32]
    float* attn = out + BATCH * CIN * NPIX;            // [16,8,1024,9]

    float* ws  = (float*)d_ws;
    float* qs  = ws;                                   // 16384*512 (aliased as po)
    float* ks  = qs + 16384 * INNER;
    float* vs  = ks + 16384 * INNER;
    float* Wt  = vs + 16384 * INNER;                   // 256*1536
    float* Wot = Wt + CIN * NQKV;                      // 512*256

    transpose_w<<<2048, 256, 0, stream>>>(Wq, Wkv, Wo, Wt, Wot);

    dim3 g1(NQKV / 64, 16384 / 64);                    // 24 x 256
    qkv_gemm<<<g1, 256, 0, stream>>>(x, Wt, qs, ks, vs);

    attn_kernel<<<(16384 * HEADS) / 4, 256, 0, stream>>>(qs, ks, vs, qs, attn);

    dim3 g2(CIN / 64, 16384 / 64);                     // 4 x 256
    out_gemm<<<g2, 256, 0, stream>>>(qs, Wot, bo, out);
}

// Round 2
// 237.490 us; speedup vs baseline: 1.8321x; 1.8321x over previous
//
#include <hip/hip_runtime.h>

#define NPIX   1024
#define BATCH  16
#define CIN    256
#define NQKV   1536
#define INNER  512
#define HEADS  8
#define DH     64

typedef __attribute__((ext_vector_type(8))) short short8;   // 8 bf16 = 4 VGPRs
typedef __attribute__((ext_vector_type(4))) float f32x4;

__device__ __forceinline__ ushort f2b(float f) {
    union { float f; unsigned u; } v; v.f = f;
    unsigned r = v.u + 0x7fffu + ((v.u >> 16) & 1u);   // RNE
    return (ushort)(r >> 16);
}
__device__ __forceinline__ float b2f(ushort u) {
    union { float f; unsigned u; } v; v.u = ((unsigned)u) << 16; return v.f;
}
__device__ __forceinline__ void async16(const void* g, void* l) {
    __builtin_amdgcn_global_load_lds((const __attribute__((address_space(1))) void*)g,
                                     (__attribute__((address_space(3))) void*)l, 16, 0, 0);
}

// ---------------------------------------------------------------------------
// prep_x: x [b][c][p] f32 -> xT [b][p][c] bf16  (transpose + convert)
// ---------------------------------------------------------------------------
__global__ __launch_bounds__(256) void prep_x(const float* __restrict__ x,
                                              ushort* __restrict__ xT) {
    __shared__ float tile[32][33];
    const int b  = blockIdx.z;
    const int p0 = blockIdx.x * 32;
    const int c0 = blockIdx.y * 32;
    const int tx = threadIdx.x, ty = threadIdx.y;   // 32 x 8
#pragma unroll
    for (int i = 0; i < 4; i++) {
        int c = ty + i * 8;
        tile[c][tx] = x[(b * CIN + c0 + c) * NPIX + p0 + tx];
    }
    __syncthreads();
#pragma unroll
    for (int i = 0; i < 4; i++) {
        int p = ty + i * 8;
        xT[(b * NPIX + p0 + p) * CIN + c0 + tx] = f2b(tile[tx][p]);
    }
}

// ---------------------------------------------------------------------------
// prep_w: Wq/Wkv -> Wqkv_b [1536][256] bf16 (k-minor, no transpose);
//         Wo [256][512] -> bf16 (already k-minor)
// ---------------------------------------------------------------------------
__global__ __launch_bounds__(256) void prep_w(const float* __restrict__ Wq,
        const float* __restrict__ Wkv, const float* __restrict__ Wo,
        ushort* __restrict__ Wqkv_b, ushort* __restrict__ Wob) {
    int i = blockIdx.x * 256 + threadIdx.x;
    if (i < NQKV * CIN)
        Wqkv_b[i] = f2b(i < INNER * CIN ? Wq[i] : Wkv[i - INNER * CIN]);
    int j = i - NQKV * CIN;
    if (j >= 0 && j < CIN * INNER)
        Wob[j] = f2b(Wo[j]);
}

// ---------------------------------------------------------------------------
// GEMM1 (MFMA): D[o][p] = sum_c Wqkv_b[o][c] * xT[p][c]
// tile 128(o) x 128(p), BK=32, 4 waves (2x2 quadrants), 4x4 frags of 16x16x32.
// Output qkv[m][o] bf16 (per-lane 4 consecutive o -> 8B stores).
// ---------------------------------------------------------------------------
__global__ __launch_bounds__(256) void gemm_qkv(const ushort* __restrict__ xT,
        const ushort* __restrict__ Wb, ushort* __restrict__ qkv) {
    __shared__ ushort Ws[128][32];   // rows = o
    __shared__ ushort Xs[128][32];   // rows = p
    const int m0 = blockIdx.x * 128;
    const int n0 = blockIdx.y * 128;
    const int t    = threadIdx.x;
    const int wave = t >> 6, lane = t & 63;
    const int wo = (wave & 1) * 64, wp = (wave >> 1) * 64;
    const int lrow = lane & 15, loct = lane >> 4;

    const int srow = t >> 2;            // staging row (0..63)
    const int skb  = (t & 3) * 8;       // staging k offset (ushorts)
    const ushort* gA = Wb + (n0 + srow) * CIN + skb;
    const ushort* gB = xT + (m0 + srow) * CIN + skb;
    ushort* ldsA0 = &Ws[wave * 16][0];
    ushort* ldsA1 = &Ws[64 + wave * 16][0];
    ushort* ldsB0 = &Xs[wave * 16][0];
    ushort* ldsB1 = &Xs[64 + wave * 16][0];

    f32x4 acc[4][4];
#pragma unroll
    for (int i = 0; i < 4; i++)
#pragma unroll
        for (int j = 0; j < 4; j++) acc[i][j] = (f32x4){0.f, 0.f, 0.f, 0.f};

    for (int c0 = 0; c0 < CIN; c0 += 32) {
        async16(gA + c0, ldsA0);
        async16(gA + 64 * CIN + c0, ldsA1);
        async16(gB + c0, ldsB0);
        async16(gB + 64 * CIN + c0, ldsB1);
        __syncthreads();
        short8 a[4], bb[4];
#pragma unroll
        for (int i = 0; i < 4; i++)
            a[i] = *reinterpret_cast<const short8*>(&Ws[wo + i * 16 + lrow][loct * 8]);
#pragma unroll
        for (int j = 0; j < 4; j++)
            bb[j] = *reinterpret_cast<const short8*>(&Xs[wp + j * 16 + lrow][loct * 8]);
#pragma unroll
        for (int i = 0; i < 4; i++)
#pragma unroll
            for (int j = 0; j < 4; j++)
                acc[i][j] = __builtin_amdgcn_mfma_f32_16x16x32_bf16(a[i], bb[j], acc[i][j], 0, 0, 0);
        __syncthreads();
    }
#pragma unroll
    for (int i = 0; i < 4; i++)
#pragma unroll
        for (int j = 0; j < 4; j++) {
            int gm = m0 + wp + j * 16 + lrow;
            int go = n0 + wo + i * 16 + loct * 4;
            ushort4 pk = make_ushort4(f2b(acc[i][j].x), f2b(acc[i][j].y),
                                      f2b(acc[i][j].z), f2b(acc[i][j].w));
            *reinterpret_cast<ushort4*>(&qkv[gm * NQKV + go]) = pk;
        }
}

// ---------------------------------------------------------------------------
// Attention: one wave per (m, h), lane = d. Zero-pad softmax semantics.
// ---------------------------------------------------------------------------
__global__ __launch_bounds__(256) void attn_kernel(const ushort* __restrict__ qkv,
        ushort* __restrict__ po, float* __restrict__ attn_out) {
    const int gw   = blockIdx.x * 4 + (threadIdx.x >> 6);
    const int lane = threadIdx.x & 63;
    const int h = gw & 7;
    const int m = gw >> 3;
    const int b = m >> 10;
    const int p = m & 1023;
    const int py = p >> 5, px = p & 31;
    const int hd = h * DH + lane;

    const float q = b2f(qkv[m * NQKV + hd]);

    float dots[9];
    int   nb[9];
    bool  ok[9];
#pragma unroll
    for (int w = 0; w < 9; w++) {
        int dy = w / 3 - 1, dx = w % 3 - 1;
        int ny = py + dy, nx = px + dx;
        bool in = ((unsigned)ny < 32u) && ((unsigned)nx < 32u);
        ok[w] = in;
        int nm = b * NPIX + ny * 32 + nx;
        nb[w] = nm;
        float d = 0.f;
        if (in) d = q * b2f(qkv[nm * NQKV + 512 + hd]);
#pragma unroll
        for (int off = 32; off; off >>= 1) d += __shfl_xor(d, off);
        dots[w] = d * 0.125f;
    }

    float mx = dots[0];
#pragma unroll
    for (int w = 1; w < 9; w++) mx = fmaxf(mx, dots[w]);
    float e[9], s = 0.f;
#pragma unroll
    for (int w = 0; w < 9; w++) { e[w] = __expf(dots[w] - mx); s += e[w]; }
    const float inv = 1.f / s;

    float o = 0.f;
#pragma unroll
    for (int w = 0; w < 9; w++)
        if (ok[w]) o += (e[w] * inv) * b2f(qkv[nb[w] * NQKV + 1024 + hd]);
    po[m * INNER + hd] = f2b(o);

#pragma unroll
    for (int w = 0; w < 9; w++)
        if (lane == w)
            attn_out[((b * HEADS + h) * NPIX + p) * 9 + w] = e[w] * inv;
}

// ---------------------------------------------------------------------------
// GEMM2 (MFMA): D[p][o] = sum_i po[p][i] * Wob[o][i]  (+ bias)
// tile 128(p) x 128(o), BK=32. float4 stores along p into out[b][o][p].
// ---------------------------------------------------------------------------
__global__ __launch_bounds__(256) void gemm_out(const ushort* __restrict__ po,
        const ushort* __restrict__ Wob, const float* __restrict__ bo,
        float* __restrict__ out) {
    __shared__ ushort As[128][32];   // rows = p
    __shared__ ushort Bs[128][32];   // rows = o
    const int m0 = blockIdx.x * 128;
    const int n0 = blockIdx.y * 128;
    const int t    = threadIdx.x;
    const int wave = t >> 6, lane = t & 63;
    const int wm = (wave >> 1) * 64, wn = (wave & 1) * 64;
    const int lrow = lane & 15, loct = lane >> 4;

    const int srow = t >> 2;
    const int skb  = (t & 3) * 8;
    const ushort* gA = po  + (m0 + srow) * INNER + skb;
    const ushort* gB = Wob + (n0 + srow) * INNER + skb;
    ushort* ldsA0 = &As[wave * 16][0];
    ushort* ldsA1 = &As[64 + wave * 16][0];
    ushort* ldsB0 = &Bs[wave * 16][0];
    ushort* ldsB1 = &Bs[64 + wave * 16][0];

    f32x4 acc[4][4];
#pragma unroll
    for (int i = 0; i < 4; i++)
#pragma unroll
        for (int j = 0; j < 4; j++) acc[i][j] = (f32x4){0.f, 0.f, 0.f, 0.f};

    for (int c0 = 0; c0 < INNER; c0 += 32) {
        async16(gA + c0, ldsA0);
        async16(gA + 64 * INNER + c0, ldsA1);
        async16(gB + c0, ldsB0);
        async16(gB + 64 * INNER + c0, ldsB1);
        __syncthreads();
        short8 a[4], bb[4];
#pragma unroll
        for (int i = 0; i < 4; i++)
            a[i] = *reinterpret_cast<const short8*>(&As[wm + i * 16 + lrow][loct * 8]);
#pragma unroll
        for (int j = 0; j < 4; j++)
            bb[j] = *reinterpret_cast<const short8*>(&Bs[wn + j * 16 + lrow][loct * 8]);
#pragma unroll
        for (int i = 0; i < 4; i++)
#pragma unroll
            for (int j = 0; j < 4; j++)
                acc[i][j] = __builtin_amdgcn_mfma_f32_16x16x32_bf16(a[i], bb[j], acc[i][j], 0, 0, 0);
        __syncthreads();
    }
    const int bb_ = m0 >> 10;
    const int p0  = m0 & 1023;
#pragma unroll
    for (int i = 0; i < 4; i++)
#pragma unroll
        for (int j = 0; j < 4; j++) {
            int o  = n0 + wn + j * 16 + lrow;
            int pp = p0 + wm + i * 16 + loct * 4;
            float bias = bo[o];
            float4 v = make_float4(acc[i][j].x + bias, acc[i][j].y + bias,
                                   acc[i][j].z + bias, acc[i][j].w + bias);
            *reinterpret_cast<float4*>(&out[(bb_ * CIN + o) * NPIX + pp]) = v;
        }
}

// ---------------------------------------------------------------------------
extern "C" void kernel_launch(void* const* d_in, const int* in_sizes, int n_in,
                              void* d_out, int out_size, void* d_ws, size_t ws_size,
                              hipStream_t stream) {
    const float* x   = (const float*)d_in[0];
    const float* Wq  = (const float*)d_in[1];
    const float* Wkv = (const float*)d_in[2];
    const float* Wo  = (const float*)d_in[3];
    const float* bo  = (const float*)d_in[4];

    float* out  = (float*)d_out;
    float* attn = out + BATCH * CIN * NPIX;

    ushort* xT     = (ushort*)d_ws;               // 16384*256
    ushort* Wqkv_b = xT + 16384 * CIN;            // 1536*256
    ushort* Wob    = Wqkv_b + NQKV * CIN;         // 256*512
    ushort* qkv    = Wob + CIN * INNER;           // 16384*1536
    ushort* po     = qkv + 16384 * NQKV;          // 16384*512

    prep_x<<<dim3(32, 8, BATCH), dim3(32, 8), 0, stream>>>(x, xT);
    prep_w<<<2048, 256, 0, stream>>>(Wq, Wkv, Wo, Wqkv_b, Wob);

    gemm_qkv<<<dim3(128, 12), 256, 0, stream>>>(xT, Wqkv_b, qkv);

    attn_kernel<<<(16384 * HEADS) / 4, 256, 0, stream>>>(qkv, po, attn);

    gemm_out<<<dim3(128, 2), 256, 0, stream>>>(po, Wob, bo, out);
}

// Round 3
// 139.775 us; speedup vs baseline: 3.1128x; 1.6991x over previous
//
#include <hip/hip_runtime.h>

#define NPIX   1024
#define BATCH  16
#define CIN    256
#define NQKV   1536
#define INNER  512
#define HEADS  8
#define DH     64

typedef __attribute__((ext_vector_type(8))) short short8;   // 8 bf16 = 4 VGPRs
typedef __attribute__((ext_vector_type(4))) float f32x4;

__device__ __forceinline__ ushort f2b(float f) {
    union { float f; unsigned u; } v; v.f = f;
    unsigned r = v.u + 0x7fffu + ((v.u >> 16) & 1u);   // RNE
    return (ushort)(r >> 16);
}
__device__ __forceinline__ float b2f(ushort u) {
    union { float f; unsigned u; } v; v.u = ((unsigned)u) << 16; return v.f;
}
__device__ __forceinline__ void async16(const void* g, void* l) {
    __builtin_amdgcn_global_load_lds((const __attribute__((address_space(1))) void*)g,
                                     (__attribute__((address_space(3))) void*)l, 16, 0, 0);
}

// ---------------------------------------------------------------------------
// prep_x: x [b][c][p] f32 -> xT [b][p][c] bf16  (transpose + convert)
// ---------------------------------------------------------------------------
__global__ __launch_bounds__(256) void prep_x(const float* __restrict__ x,
                                              ushort* __restrict__ xT) {
    __shared__ float tile[32][33];
    const int b  = blockIdx.z;
    const int p0 = blockIdx.x * 32;
    const int c0 = blockIdx.y * 32;
    const int tx = threadIdx.x, ty = threadIdx.y;   // 32 x 8
#pragma unroll
    for (int i = 0; i < 4; i++) {
        int c = ty + i * 8;
        tile[c][tx] = x[(b * CIN + c0 + c) * NPIX + p0 + tx];
    }
    __syncthreads();
#pragma unroll
    for (int i = 0; i < 4; i++) {
        int p = ty + i * 8;
        xT[(b * NPIX + p0 + p) * CIN + c0 + tx] = f2b(tile[tx][p]);
    }
}

// ---------------------------------------------------------------------------
// prep_w: Wq/Wkv -> Wqkv_b [1536][256] bf16 (k-minor); Wo -> bf16
// ---------------------------------------------------------------------------
__global__ __launch_bounds__(256) void prep_w(const float* __restrict__ Wq,
        const float* __restrict__ Wkv, const float* __restrict__ Wo,
        ushort* __restrict__ Wqkv_b, ushort* __restrict__ Wob) {
    int i = blockIdx.x * 256 + threadIdx.x;
    if (i < NQKV * CIN)
        Wqkv_b[i] = f2b(i < INNER * CIN ? Wq[i] : Wkv[i - INNER * CIN]);
    int j = i - NQKV * CIN;
    if (j >= 0 && j < CIN * INNER)
        Wob[j] = f2b(Wo[j]);
}

// ---------------------------------------------------------------------------
// GEMM1 (MFMA): D[o][p] = sum_c Wqkv_b[o][c] * xT[p][c]
// ---------------------------------------------------------------------------
__global__ __launch_bounds__(256) void gemm_qkv(const ushort* __restrict__ xT,
        const ushort* __restrict__ Wb, ushort* __restrict__ qkv) {
    __shared__ ushort Ws[128][32];   // rows = o
    __shared__ ushort Xs[128][32];   // rows = p
    const int m0 = blockIdx.x * 128;
    const int n0 = blockIdx.y * 128;
    const int t    = threadIdx.x;
    const int wave = t >> 6, lane = t & 63;
    const int wo = (wave & 1) * 64, wp = (wave >> 1) * 64;
    const int lrow = lane & 15, loct = lane >> 4;

    const int srow = t >> 2;
    const int skb  = (t & 3) * 8;
    const ushort* gA = Wb + (n0 + srow) * CIN + skb;
    const ushort* gB = xT + (m0 + srow) * CIN + skb;
    ushort* ldsA0 = &Ws[wave * 16][0];
    ushort* ldsA1 = &Ws[64 + wave * 16][0];
    ushort* ldsB0 = &Xs[wave * 16][0];
    ushort* ldsB1 = &Xs[64 + wave * 16][0];

    f32x4 acc[4][4];
#pragma unroll
    for (int i = 0; i < 4; i++)
#pragma unroll
        for (int j = 0; j < 4; j++) acc[i][j] = (f32x4){0.f, 0.f, 0.f, 0.f};

    for (int c0 = 0; c0 < CIN; c0 += 32) {
        async16(gA + c0, ldsA0);
        async16(gA + 64 * CIN + c0, ldsA1);
        async16(gB + c0, ldsB0);
        async16(gB + 64 * CIN + c0, ldsB1);
        __syncthreads();
        short8 a[4], bb[4];
#pragma unroll
        for (int i = 0; i < 4; i++)
            a[i] = *reinterpret_cast<const short8*>(&Ws[wo + i * 16 + lrow][loct * 8]);
#pragma unroll
        for (int j = 0; j < 4; j++)
            bb[j] = *reinterpret_cast<const short8*>(&Xs[wp + j * 16 + lrow][loct * 8]);
#pragma unroll
        for (int i = 0; i < 4; i++)
#pragma unroll
            for (int j = 0; j < 4; j++)
                acc[i][j] = __builtin_amdgcn_mfma_f32_16x16x32_bf16(a[i], bb[j], acc[i][j], 0, 0, 0);
        __syncthreads();
    }
#pragma unroll
    for (int i = 0; i < 4; i++)
#pragma unroll
        for (int j = 0; j < 4; j++) {
            int gm = m0 + wp + j * 16 + lrow;
            int go = n0 + wo + i * 16 + loct * 4;
            ushort4 pk = make_ushort4(f2b(acc[i][j].x), f2b(acc[i][j].y),
                                      f2b(acc[i][j].z), f2b(acc[i][j].w));
            *reinterpret_cast<ushort4*>(&qkv[gm * NQKV + go]) = pk;
        }
}

// ---------------------------------------------------------------------------
// Attention: one wave per pixel m; lane = (h, d-octet): h=lane>>3, sub=lane&7.
// Each lane holds 8 d-elements in registers. All global accesses are
// contiguous 1KB per wave; window-OOB branches are wave-uniform.
// Dot reduce = 3 shfl_xor within the 8-lane group (butterfly -> all lanes
// hold the sum). Zero-pad softmax semantics preserved.
// ---------------------------------------------------------------------------
__global__ __launch_bounds__(256) void attn_kernel(const ushort* __restrict__ qkv,
        ushort* __restrict__ po, float* __restrict__ attn_out) {
    const int m    = blockIdx.x * 4 + (threadIdx.x >> 6);
    const int lane = threadIdx.x & 63;
    const int h = lane >> 3, sub = lane & 7;
    const int b = m >> 10;
    const int p = m & 1023;
    const int py = p >> 5, px = p & 31;
    const int hd8 = h * DH + sub * 8;

    short8 qv = *reinterpret_cast<const short8*>(&qkv[m * NQKV + hd8]);
    float qf[8];
#pragma unroll
    for (int j = 0; j < 8; j++) qf[j] = b2f((ushort)qv[j]);

    float dots[9];
    int   nb[9];
    bool  ok[9];
#pragma unroll
    for (int w = 0; w < 9; w++) {
        int dy = w / 3 - 1, dx = w % 3 - 1;
        int ny = py + dy, nx = px + dx;
        bool in = ((unsigned)ny < 32u) && ((unsigned)nx < 32u);
        ok[w] = in;
        int nm = b * NPIX + ny * 32 + nx;
        nb[w] = nm;
        float d = 0.f;
        if (in) {
            short8 kv8 = *reinterpret_cast<const short8*>(&qkv[nm * NQKV + 512 + hd8]);
#pragma unroll
            for (int j = 0; j < 8; j++) d = fmaf(qf[j], b2f((ushort)kv8[j]), d);
        }
        d += __shfl_xor(d, 1);
        d += __shfl_xor(d, 2);
        d += __shfl_xor(d, 4);
        dots[w] = d * 0.125f;   // OOB: exact 0 (zero-pad semantics)
    }

    float mx = dots[0];
#pragma unroll
    for (int w = 1; w < 9; w++) mx = fmaxf(mx, dots[w]);
    float e[9], s = 0.f;
#pragma unroll
    for (int w = 0; w < 9; w++) { e[w] = __expf(dots[w] - mx); s += e[w]; }
    const float inv = 1.f / s;

    float o[8] = {};
#pragma unroll
    for (int w = 0; w < 9; w++) {
        if (ok[w]) {
            short8 vv = *reinterpret_cast<const short8*>(&qkv[nb[w] * NQKV + 1024 + hd8]);
            float pw = e[w] * inv;
#pragma unroll
            for (int j = 0; j < 8; j++) o[j] = fmaf(pw, b2f((ushort)vv[j]), o[j]);
        }
    }
    short8 r;
#pragma unroll
    for (int j = 0; j < 8; j++) r[j] = (short)f2b(o[j]);
    *reinterpret_cast<short8*>(&po[m * INNER + hd8]) = r;

    float* ab = &attn_out[((b * HEADS + h) * NPIX + p) * 9];
    ab[sub] = e[sub] * inv;
    if (sub == 0) ab[8] = e[8] * inv;
}

// ---------------------------------------------------------------------------
// GEMM2 (MFMA): D[p][o] = sum_i po[p][i] * Wob[o][i]  (+ bias)
// ---------------------------------------------------------------------------
__global__ __launch_bounds__(256) void gemm_out(const ushort* __restrict__ po,
        const ushort* __restrict__ Wob, const float* __restrict__ bo,
        float* __restrict__ out) {
    __shared__ ushort As[128][32];   // rows = p
    __shared__ ushort Bs[128][32];   // rows = o
    const int m0 = blockIdx.x * 128;
    const int n0 = blockIdx.y * 128;
    const int t    = threadIdx.x;
    const int wave = t >> 6, lane = t & 63;
    const int wm = (wave >> 1) * 64, wn = (wave & 1) * 64;
    const int lrow = lane & 15, loct = lane >> 4;

    const int srow = t >> 2;
    const int skb  = (t & 3) * 8;
    const ushort* gA = po  + (m0 + srow) * INNER + skb;
    const ushort* gB = Wob + (n0 + srow) * INNER + skb;
    ushort* ldsA0 = &As[wave * 16][0];
    ushort* ldsA1 = &As[64 + wave * 16][0];
    ushort* ldsB0 = &Bs[wave * 16][0];
    ushort* ldsB1 = &Bs[64 + wave * 16][0];

    f32x4 acc[4][4];
#pragma unroll
    for (int i = 0; i < 4; i++)
#pragma unroll
        for (int j = 0; j < 4; j++) acc[i][j] = (f32x4){0.f, 0.f, 0.f, 0.f};

    for (int c0 = 0; c0 < INNER; c0 += 32) {
        async16(gA + c0, ldsA0);
        async16(gA + 64 * INNER + c0, ldsA1);
        async16(gB + c0, ldsB0);
        async16(gB + 64 * INNER + c0, ldsB1);
        __syncthreads();
        short8 a[4], bb[4];
#pragma unroll
        for (int i = 0; i < 4; i++)
            a[i] = *reinterpret_cast<const short8*>(&As[wm + i * 16 + lrow][loct * 8]);
#pragma unroll
        for (int j = 0; j < 4; j++)
            bb[j] = *reinterpret_cast<const short8*>(&Bs[wn + j * 16 + lrow][loct * 8]);
#pragma unroll
        for (int i = 0; i < 4; i++)
#pragma unroll
            for (int j = 0; j < 4; j++)
                acc[i][j] = __builtin_amdgcn_mfma_f32_16x16x32_bf16(a[i], bb[j], acc[i][j], 0, 0, 0);
        __syncthreads();
    }
    const int bb_ = m0 >> 10;
    const int p0  = m0 & 1023;
#pragma unroll
    for (int i = 0; i < 4; i++)
#pragma unroll
        for (int j = 0; j < 4; j++) {
            int o  = n0 + wn + j * 16 + lrow;
            int pp = p0 + wm + i * 16 + loct * 4;
            float bias = bo[o];
            float4 v = make_float4(acc[i][j].x + bias, acc[i][j].y + bias,
                                   acc[i][j].z + bias, acc[i][j].w + bias);
            *reinterpret_cast<float4*>(&out[(bb_ * CIN + o) * NPIX + pp]) = v;
        }
}

// ---------------------------------------------------------------------------
extern "C" void kernel_launch(void* const* d_in, const int* in_sizes, int n_in,
                              void* d_out, int out_size, void* d_ws, size_t ws_size,
                              hipStream_t stream) {
    const float* x   = (const float*)d_in[0];
    const float* Wq  = (const float*)d_in[1];
    const float* Wkv = (const float*)d_in[2];
    const float* Wo  = (const float*)d_in[3];
    const float* bo  = (const float*)d_in[4];

    float* out  = (float*)d_out;
    float* attn = out + BATCH * CIN * NPIX;

    ushort* xT     = (ushort*)d_ws;               // 16384*256
    ushort* Wqkv_b = xT + 16384 * CIN;            // 1536*256
    ushort* Wob    = Wqkv_b + NQKV * CIN;         // 256*512
    ushort* qkv    = Wob + CIN * INNER;           // 16384*1536
    ushort* po     = qkv + 16384 * NQKV;          // 16384*512

    prep_x<<<dim3(32, 8, BATCH), dim3(32, 8), 0, stream>>>(x, xT);
    prep_w<<<2048, 256, 0, stream>>>(Wq, Wkv, Wo, Wqkv_b, Wob);

    gemm_qkv<<<dim3(128, 12), 256, 0, stream>>>(xT, Wqkv_b, qkv);

    attn_kernel<<<16384 / 4, 256, 0, stream>>>(qkv, po, attn);

    gemm_out<<<dim3(128, 2), 256, 0, stream>>>(po, Wob, bo, out);
}